// Round 3
// baseline (76.610 us; speedup 1.0000x reference)
//
#include <hip/hip_runtime.h>

// Fused 3x3 neighborhood-attention, two-kernel version.
//   K1 (coef_kernel): per-pixel 9-neighbor cosine sims -> softmax -> coef[9]
//                     (patch l2-norm folded into coef), written to d_ws planes.
//   K2 (apply_kernel): out[c,p] = exp(-(nbr-ref)^2) * sum_k coef_k * nbr[c,p+dk]
//                     float4-vectorized along x, margins via __shfl.
// Shapes: [b=2, c=64, h=256, w=256] fp32.

constexpr int C = 64, H = 256, W = 256, HW = H * W;
constexpr int B = 2;
constexpr int PIX = B * HW;        // 131072 pixels
constexpr int CG = 16;             // channels per thread in K1

// ---------------- K1: coefficient kernel ----------------
// 4 lanes per pixel (16 channels each), 16 pixels per wave (64B coalesced).
__global__ __launch_bounds__(256) void coef_kernel(const float* __restrict__ nbr,
                                                   const float* __restrict__ ref,
                                                   float* __restrict__ coef) {
  const int tid  = threadIdx.x;
  const int lane = tid & 63;
  const int wv   = tid >> 6;         // wave in block 0..3
  const int px   = lane & 15;        // pixel slot 0..15
  const int cgl  = lane >> 4;        // channel group 0..3

  const int pix = blockIdx.x * 64 + wv * 16 + px;  // b*HW + y*W + x
  const int b   = pix >> 16;
  const int p   = pix & (HW - 1);
  const int y   = p >> 8;
  const int x   = p & (W - 1);

  const int ym = (y == 0)     ? 1     : y - 1;
  const int yp = (y == H - 1) ? H - 2 : y + 1;
  const int xm = (x == 0)     ? 1     : x - 1;
  const int xp = (x == W - 1) ? W - 2 : x + 1;

  int off[9];
  off[0] = ym * W + xm; off[1] = ym * W + x; off[2] = ym * W + xp;
  off[3] = y  * W + xm; off[4] = y  * W + x; off[5] = y  * W + xp;
  off[6] = yp * W + xm; off[7] = yp * W + x; off[8] = yp * W + xp;
  const int ctr = y * W + x;

  const float* nb = nbr + ((size_t)b * C + cgl * CG) * HW;
  const float* rb = ref + ((size_t)b * C + cgl * CG) * HW;

  float sr = 0.f;
  float dot[9], ss[9];
#pragma unroll
  for (int k = 0; k < 9; ++k) { dot[k] = 0.f; ss[k] = 0.f; }

#pragma unroll 4
  for (int j = 0; j < CG; ++j) {
    const float r = rb[j * HW + ctr];
    sr = fmaf(r, r, sr);
#pragma unroll
    for (int k = 0; k < 9; ++k) {
      const float v = nb[j * HW + off[k]];   // consumed immediately: low reg pressure
      dot[k] = fmaf(r, v, dot[k]);
      ss[k]  = fmaf(v, v, ss[k]);
    }
  }

  // reduce the 19 partials across the 4 lanes of this pixel (masks 16, 32)
#pragma unroll
  for (int m = 16; m < 64; m <<= 1) {
    sr += __shfl_xor(sr, m);
#pragma unroll
    for (int k = 0; k < 9; ++k) {
      dot[k] += __shfl_xor(dot[k], m);
      ss[k]  += __shfl_xor(ss[k], m);
    }
  }

  // normalize + softmax (replicated in all 4 lanes; only cgl==0 stores)
  const float invr = 1.0f / fmaxf(sqrtf(sr), 1e-12f);
  float d[9], invp[9];
  float mx = -INFINITY;
#pragma unroll
  for (int k = 0; k < 9; ++k) {
    invp[k] = 1.0f / fmaxf(sqrtf(ss[k]), 1e-12f);
    d[k]    = dot[k] * invr * invp[k];
    mx      = fmaxf(mx, d[k]);
  }
  float s = 0.f;
  float cf[9];
#pragma unroll
  for (int k = 0; k < 9; ++k) {
    const float e = __expf(d[k] - mx);
    cf[k] = e;
    s += e;
  }
  const float sinv = 1.0f / s;

  if (cgl == 0) {
#pragma unroll
    for (int k = 0; k < 9; ++k) coef[k * PIX + pix] = cf[k] * sinv * invp[k];
  }
}

// ---------------- K2: apply kernel ----------------
// Thread = 4 consecutive x pixels (quad) x 2 channels. One wave = one full row.
__global__ __launch_bounds__(256) void apply_kernel(const float* __restrict__ nbr,
                                                    const float* __restrict__ ref,
                                                    const float* __restrict__ coef,
                                                    float* __restrict__ out) {
  const int gid  = blockIdx.x * 256 + threadIdx.x;
  const int lane = gid & 63;                 // quad index in row; x0 = lane*4
  const int x0   = lane * 4;
  const int t    = gid >> 6;                 // (b, cpair, y)
  const int y    = t & 255;
  const int u    = t >> 8;                   // 0..63
  const int b    = u >> 5;
  const int c0   = (u & 31) * 2;

  const int ym = (y == 0)     ? 1     : y - 1;
  const int yp = (y == H - 1) ? H - 2 : y + 1;

  const float* n0 = nbr + ((size_t)b * C + c0) * HW;
  const float* n1 = n0 + HW;
  const float* r0p = ref + ((size_t)b * C + c0) * HW;
  float*       o0 = out + ((size_t)b * C + c0) * HW;

  // row loads (float4) for both channels
  const float4 a0 = *(const float4*)(n0 + ym * W + x0);
  const float4 a1 = *(const float4*)(n0 + y  * W + x0);
  const float4 a2 = *(const float4*)(n0 + yp * W + x0);
  const float4 b0 = *(const float4*)(n1 + ym * W + x0);
  const float4 b1 = *(const float4*)(n1 + y  * W + x0);
  const float4 b2 = *(const float4*)(n1 + yp * W + x0);
  const float4 f0 = *(const float4*)(r0p + y * W + x0);
  const float4 f1 = *(const float4*)(r0p + HW + y * W + x0);

  // x margins via shuffle; reflect at image edges resolves to own elements
  // left margin = value at x0-1; right margin = value at x0+4
  float La0 = __shfl(a0.w, lane - 1), Ra0 = __shfl(a0.x, lane + 1);
  float La1 = __shfl(a1.w, lane - 1), Ra1 = __shfl(a1.x, lane + 1);
  float La2 = __shfl(a2.w, lane - 1), Ra2 = __shfl(a2.x, lane + 1);
  float Lb0 = __shfl(b0.w, lane - 1), Rb0 = __shfl(b0.x, lane + 1);
  float Lb1 = __shfl(b1.w, lane - 1), Rb1 = __shfl(b1.x, lane + 1);
  float Lb2 = __shfl(b2.w, lane - 1), Rb2 = __shfl(b2.x, lane + 1);
  if (lane == 0)  { La0 = a0.y; La1 = a1.y; La2 = a2.y; Lb0 = b0.y; Lb1 = b1.y; Lb2 = b2.y; }
  if (lane == 63) { Ra0 = a0.z; Ra1 = a1.z; Ra2 = a2.z; Rb0 = b0.z; Rb1 = b1.z; Rb2 = b2.z; }

  // 6-wide row values per (channel,row): [L, q.x, q.y, q.z, q.w, R]
  float va[3][6] = {{La0, a0.x, a0.y, a0.z, a0.w, Ra0},
                    {La1, a1.x, a1.y, a1.z, a1.w, Ra1},
                    {La2, a2.x, a2.y, a2.z, a2.w, Ra2}};
  float vb[3][6] = {{Lb0, b0.x, b0.y, b0.z, b0.w, Rb0},
                    {Lb1, b1.x, b1.y, b1.z, b1.w, Rb1},
                    {Lb2, b2.x, b2.y, b2.z, b2.w, Rb2}};

  const int cbase = b * HW + y * W + x0;
  float aga[4] = {0.f, 0.f, 0.f, 0.f};
  float agb[4] = {0.f, 0.f, 0.f, 0.f};
#pragma unroll
  for (int k = 0; k < 9; ++k) {
    const float4 cf = *(const float4*)(coef + k * PIX + cbase);
    const int r  = k / 3;
    const int cx = k % 3;              // x-offset index: e + cx into 6-wide row
    const float cfe[4] = {cf.x, cf.y, cf.z, cf.w};
#pragma unroll
    for (int e = 0; e < 4; ++e) {
      aga[e] = fmaf(cfe[e], va[r][e + cx], aga[e]);
      agb[e] = fmaf(cfe[e], vb[r][e + cx], agb[e]);
    }
  }

  // wdiff = exp(-(nbr_center - ref)^2), per channel/pixel
  const float ctra[4] = {a1.x, a1.y, a1.z, a1.w};
  const float ctrb[4] = {b1.x, b1.y, b1.z, b1.w};
  const float rfa[4]  = {f0.x, f0.y, f0.z, f0.w};
  const float rfb[4]  = {f1.x, f1.y, f1.z, f1.w};
  float4 oa, ob4;
  float oae[4], obe[4];
#pragma unroll
  for (int e = 0; e < 4; ++e) {
    const float da = ctra[e] - rfa[e];
    const float db = ctrb[e] - rfb[e];
    oae[e] = aga[e] * __expf(-(da * da));
    obe[e] = agb[e] * __expf(-(db * db));
  }
  oa.x = oae[0]; oa.y = oae[1]; oa.z = oae[2]; oa.w = oae[3];
  ob4.x = obe[0]; ob4.y = obe[1]; ob4.z = obe[2]; ob4.w = obe[3];

  *(float4*)(o0 + y * W + x0) = oa;
  *(float4*)(o0 + HW + y * W + x0) = ob4;
}

// ---------------- fallback: R1 fused kernel (used if ws too small) ----------------
__global__ __launch_bounds__(256) void fused_nbr_attn(const float* __restrict__ nbr,
                                                      const float* __restrict__ ref,
                                                      float* __restrict__ out) {
  const int tid  = threadIdx.x;
  const int lane = tid & 63;
  const int wv   = tid >> 6;
  const int px   = lane & 7;
  const int cg   = lane >> 3;

  const int pix = blockIdx.x * 32 + wv * 8 + px;
  const int b   = pix >> 16;
  const int p   = pix & (HW - 1);
  const int y   = p >> 8;
  const int x   = p & (W - 1);

  const int ym = (y == 0)     ? 1     : y - 1;
  const int yp = (y == H - 1) ? H - 2 : y + 1;
  const int xm = (x == 0)     ? 1     : x - 1;
  const int xp = (x == W - 1) ? W - 2 : x + 1;

  int off[9];
  off[0] = ym * W + xm; off[1] = ym * W + x; off[2] = ym * W + xp;
  off[3] = y  * W + xm; off[4] = y  * W + x; off[5] = y  * W + xp;
  off[6] = yp * W + xm; off[7] = yp * W + x; off[8] = yp * W + xp;
  const int ctr = y * W + x;

  const float* nb = nbr + ((size_t)b * C + cg * 8) * HW;
  const float* rb = ref + ((size_t)b * C + cg * 8) * HW;
  float*       ob = out + ((size_t)b * C + cg * 8) * HW;

  float v[8][9], r[8];
#pragma unroll
  for (int j = 0; j < 8; ++j) {
    r[j] = rb[j * HW + ctr];
#pragma unroll
    for (int k = 0; k < 9; ++k) v[j][k] = nb[j * HW + off[k]];
  }
  float sr = 0.f;
  float dot[9], ss[9];
#pragma unroll
  for (int k = 0; k < 9; ++k) { dot[k] = 0.f; ss[k] = 0.f; }
#pragma unroll
  for (int j = 0; j < 8; ++j) {
    sr = fmaf(r[j], r[j], sr);
#pragma unroll
    for (int k = 0; k < 9; ++k) {
      dot[k] = fmaf(r[j], v[j][k], dot[k]);
      ss[k]  = fmaf(v[j][k], v[j][k], ss[k]);
    }
  }
#pragma unroll
  for (int m = 8; m < 64; m <<= 1) {
    sr += __shfl_xor(sr, m);
#pragma unroll
    for (int k = 0; k < 9; ++k) {
      dot[k] += __shfl_xor(dot[k], m);
      ss[k]  += __shfl_xor(ss[k], m);
    }
  }
  const float invr = 1.0f / fmaxf(sqrtf(sr), 1e-12f);
  float d[9], invp[9];
  float mx = -INFINITY;
#pragma unroll
  for (int k = 0; k < 9; ++k) {
    invp[k] = 1.0f / fmaxf(sqrtf(ss[k]), 1e-12f);
    d[k]    = dot[k] * invr * invp[k];
    mx      = fmaxf(mx, d[k]);
  }
  float s = 0.f;
  float coef[9];
#pragma unroll
  for (int k = 0; k < 9; ++k) {
    const float e = __expf(d[k] - mx);
    coef[k] = e;
    s += e;
  }
  const float sinv = 1.0f / s;
#pragma unroll
  for (int k = 0; k < 9; ++k) coef[k] *= sinv * invp[k];
#pragma unroll
  for (int j = 0; j < 8; ++j) {
    float a = 0.f;
#pragma unroll
    for (int k = 0; k < 9; ++k) a = fmaf(coef[k], v[j][k], a);
    const float diff = v[j][4] - r[j];
    const float wd   = __expf(-(diff * diff));
    ob[j * HW + ctr] = a * wd;
  }
}

extern "C" void kernel_launch(void* const* d_in, const int* in_sizes, int n_in,
                              void* d_out, int out_size, void* d_ws, size_t ws_size,
                              hipStream_t stream) {
  const float* nbr = (const float*)d_in[0];
  const float* ref = (const float*)d_in[1];
  float*       out = (float*)d_out;
  const size_t coef_bytes = (size_t)9 * PIX * sizeof(float);

  if (ws_size >= coef_bytes) {
    float* coef = (float*)d_ws;
    coef_kernel<<<dim3(PIX / 64), dim3(256), 0, stream>>>(nbr, ref, coef);
    apply_kernel<<<dim3(PIX / 4 * (C / 2) / 256), dim3(256), 0, stream>>>(nbr, ref, coef, out);
  } else {
    fused_nbr_attn<<<dim3(PIX / 32), dim3(256), 0, stream>>>(nbr, ref, out);
  }
}